// Round 6
// baseline (334.424 us; speedup 1.0000x reference)
//
#include <hip/hip_runtime.h>

#define CH   16
#define HID  128
#define DIM  64
#define NVOX (4 * DIM * DIM * DIM)

typedef __attribute__((ext_vector_type(8))) short short8;
typedef __attribute__((ext_vector_type(4))) float f32x4;

__device__ __forceinline__ unsigned short f2bf(float f) {
    union { float f; unsigned int u; } c; c.f = f;
    unsigned int u = c.u;
    u += 0x7FFFu + ((u >> 16) & 1u);          // round-nearest-even
    return (unsigned short)(u >> 16);
}

// Swapped-operand MFMA (same kappa maps as R5, verified absmax 0.03).
// Separable perception: per (z,y) row compute s = va+2vb+vc, d = va-vc over x,
// then combine over y (S or A) and z (S or A):
//   op1 (A_z S_y S_x): A_i of ps      op2 (S_z A_y S_x): S_i of pda
//   op3 (S_z S_y A_x): S_i of pds     (1/32 folded into staged W1 rows)
// OOB (z,y) rows skipped with wave-uniform branches; x-edge taps masked 0/1.
__global__ __launch_bounds__(256, 4) void nca_pass1(
    const float* __restrict__ x,  const float* __restrict__ w1,
    const float* __restrict__ b1, const float* __restrict__ w2,
    const float* __restrict__ b2, const float* __restrict__ ru,
    float* __restrict__ out, float* __restrict__ alpha_new,
    float* __restrict__ pre_life)
{
    __shared__ __align__(16) unsigned short sA1[8192];  // [n][h][g][m][j] 16KB
    __shared__ __align__(16) unsigned short sA2[2048];  // [s][g][m][j]     4KB
    __shared__ __align__(16) float sb1[HID];
    __shared__ __align__(16) float sb2[CH];

    for (int t = threadIdx.x; t < 8192; t += 256) {
        const int j = t & 7, mm = (t >> 3) & 15, gg = (t >> 7) & 3,
                  hh = (t >> 9) & 1, nn = t >> 10;
        const int op  = 2 * hh + (j & 1);
        const int row = 16 * gg + 4 * (j >> 1) + op;                // kappa1
        float wv = w1[row * HID + 16 * nn + mm];
        if (op) wv *= (1.0f / 32.0f);       // fold sobel 1/32 into W1
        sA1[t] = f2bf(wv);
    }
    for (int t = threadIdx.x; t < 2048; t += 256) {
        const int j = t & 7, mm = (t >> 3) & 15, gg = (t >> 7) & 3, ss = t >> 9;
        const int kk = 32 * ss + 16 * (j >> 2) + 4 * gg + (j & 3);  // kappa2
        sA2[t] = f2bf(w2[kk * CH + mm]);
    }
    if (threadIdx.x < HID) sb1[threadIdx.x] = b1[threadIdx.x];
    if (threadIdx.x < CH)  sb2[threadIdx.x] = b2[threadIdx.x];
    __syncthreads();

    const int lane = threadIdx.x & 63;
    const int wid  = __builtin_amdgcn_readfirstlane(threadIdx.x >> 6);
    const int m = lane & 15;
    const int g = lane >> 4;

    // each wave owns one full x-row of 64 voxels (4 MFMA tiles of 16)
    const int row = blockIdx.x * 4 + wid;     // wave-uniform (SGPR)
    const int hy = row & 63;
    const int dz = (row >> 6) & 63;
    const int bb = row >> 12;
    const int rowvox = row * 64;

    const short8* pA1 = ((const short8*)sA1) + (g * 16 + m);
    const short8* pA2 = ((const short8*)sA2) + (g * 16 + m);
    const float*  pb1 = sb1 + 4 * g;
    const float*  pb2 = sb2 + 4 * g;

    #pragma unroll 1
    for (int t = 0; t < 4; t++) {
        const int wx = 16 * t + m;
        const float ok0 = (wx > 0)  ? 1.0f : 0.0f;
        const float ok2 = (wx < 63) ? 1.0f : 0.0f;
        const int o1 = wx * CH + 4 * g;
        const int o0 = (wx > 0  ? wx - 1 : 0 ) * CH + 4 * g;
        const int o2 = (wx < 63 ? wx + 1 : 63) * CH + 4 * g;

        f32x4 zA = {0,0,0,0}, zB = {0,0,0,0}, zC = {0,0,0,0};
        f32x4 center = {0,0,0,0};
        float pre_max = -1e30f;

        #pragma unroll
        for (int i = 0; i < 3; i++) {
            const int zz = dz + i - 1;
            if ((unsigned)zz < 64u) {                    // uniform branch
                f32x4 ps = {0,0,0,0}, pds = {0,0,0,0}, pda = {0,0,0,0};
                #pragma unroll
                for (int j = 0; j < 3; j++) {
                    const int yy = hy + j - 1;
                    if ((unsigned)yy < 64u) {            // uniform branch
                        const float* prow =
                            x + (size_t)(((bb * 64 + zz) * 64 + yy) * 64) * CH;
                        f32x4 va = *(const f32x4*)(prow + o0);
                        f32x4 vb = *(const f32x4*)(prow + o1);
                        f32x4 vc = *(const f32x4*)(prow + o2);
                        va *= ok0;
                        vc *= ok2;
                        f32x4 s = va + vc;
                        #pragma unroll
                        for (int c = 0; c < 4; c++) s[c] = fmaf(2.0f, vb[c], s[c]);
                        const f32x4 d = va - vc;
                        if (j == 0)      { ps += s; pds += d; pda += s; }
                        else if (j == 1) {
                            #pragma unroll
                            for (int c = 0; c < 4; c++) {
                                ps[c]  = fmaf(2.0f, s[c], ps[c]);
                                pds[c] = fmaf(2.0f, d[c], pds[c]);
                            }
                        }
                        else             { ps += s; pds += d; pda -= s; }
                        if (i == 1 && j == 1) center = vb;
                        pre_max = fmaxf(pre_max,
                                  fmaxf(fmaxf(va[3], vb[3]), vc[3]));
                    }
                }
                if (i == 0)      { zA += ps; zB += pda; zC += pds; }
                else if (i == 1) {
                    #pragma unroll
                    for (int c = 0; c < 4; c++) {
                        zB[c] = fmaf(2.0f, pda[c], zB[c]);
                        zC[c] = fmaf(2.0f, pds[c], zC[c]);
                    }
                }
                else             { zA -= ps; zB += pda; zC += pds; }
            }
        }

        short8 a0, a1;                       // B-frags: Y[m][kappa1(h,g,j)]
        #pragma unroll
        for (int c = 0; c < 4; c++) {
            a0[2 * c + 0] = (short)f2bf(center[c]);   // op0 (ident)
            a0[2 * c + 1] = (short)f2bf(zA[c]);       // op1
            a1[2 * c + 0] = (short)f2bf(zB[c]);       // op2
            a1[2 * c + 1] = (short)f2bf(zC[c]);       // op3
        }

        // stage 1: 8 n-tiles; pack relu(H) to bf16 immediately
        short8 pbf[4];
        #pragma unroll
        for (int n = 0; n < 8; n++) {
            f32x4 h = *(const f32x4*)(pb1 + 16 * n);   // broadcast LDS read
            h = __builtin_amdgcn_mfma_f32_16x16x32_bf16(pA1[(2 * n + 0) * 64], a0, h, 0, 0, 0);
            h = __builtin_amdgcn_mfma_f32_16x16x32_bf16(pA1[(2 * n + 1) * 64], a1, h, 0, 0, 0);
            #pragma unroll
            for (int r = 0; r < 4; r++)
                pbf[n >> 1][((n & 1) << 2) + r] = (short)f2bf(fmaxf(h[r], 0.0f));
        }

        // stage 2: B-frag is the lane's own packed stage-1 outputs
        f32x4 e = *(const f32x4*)pb2;
        #pragma unroll
        for (int s = 0; s < 4; s++)
            e = __builtin_amdgcn_mfma_f32_16x16x32_bf16(pA2[s * 64], pbf[s], e, 0, 0, 0);

        // epilogue: lane (m,g) owns voxel m, channels 4g..4g+3
        const int vox = rowvox + wx;
        const float mask = (ru[vox] <= 0.5f) ? 1.0f : 0.0f;
        f32x4 xn;
        #pragma unroll
        for (int r = 0; r < 4; r++) xn[r] = fmaf(e[r], mask, center[r]);
        *(f32x4*)(out + (size_t)vox * CH + 4 * g) = xn;
        if (g == 0) {
            alpha_new[vox] = xn[3];
            pre_life[vox]  = (pre_max > 0.1f) ? 1.0f : 0.0f;
        }
    }
}

__global__ __launch_bounds__(256) void nca_pass2(
    const float* __restrict__ alpha_new, const float* __restrict__ pre_life,
    float* __restrict__ out)
{
    const int idx = blockIdx.x * 256 + threadIdx.x;
    const int wx = idx & 63;
    const int hy = (idx >> 6) & 63;
    const int dz = (idx >> 12) & 63;

    float m = -1e30f;
    #pragma unroll
    for (int i = 0; i < 3; i++) {
        const int zz = dz + i - 1;
        if ((unsigned)zz >= 64u) continue;
        #pragma unroll
        for (int j = 0; j < 3; j++) {
            const int yy = hy + j - 1;
            if ((unsigned)yy >= 64u) continue;
            #pragma unroll
            for (int k = 0; k < 3; k++) {
                const int xx = wx + k - 1;
                if ((unsigned)xx >= 64u) continue;
                m = fmaxf(m, alpha_new[idx + (i - 1) * 4096 + (j - 1) * 64 + (k - 1)]);
            }
        }
    }
    const float life = (m > 0.1f && pre_life[idx] > 0.5f) ? 1.0f : 0.0f;

    float4* p = (float4*)(out + (size_t)idx * CH);
    #pragma unroll
    for (int q = 0; q < 4; q++) {
        float4 v = p[q];
        v.x *= life; v.y *= life; v.z *= life; v.w *= life;
        p[q] = v;
    }
}

extern "C" void kernel_launch(void* const* d_in, const int* in_sizes, int n_in,
                              void* d_out, int out_size, void* d_ws, size_t ws_size,
                              hipStream_t stream) {
    const float* x  = (const float*)d_in[0];
    const float* w1 = (const float*)d_in[1];
    const float* b1 = (const float*)d_in[2];
    const float* w2 = (const float*)d_in[3];
    const float* b2 = (const float*)d_in[4];
    const float* ru = (const float*)d_in[5];
    float* out = (float*)d_out;

    float* alpha_new = (float*)d_ws;
    float* pre_life  = alpha_new + NVOX;

    // 16384 x-rows, 4 rows (waves) per block
    hipLaunchKernelGGL(nca_pass1, dim3(4096), dim3(256), 0, stream,
                       x, w1, b1, w2, b2, ru, out, alpha_new, pre_life);
    hipLaunchKernelGGL(nca_pass2, dim3(NVOX / 256), dim3(256), 0, stream,
                       alpha_new, pre_life, out);
}

// Round 7
// 198.031 us; speedup vs baseline: 1.6887x; 1.6887x over previous
//
#include <hip/hip_runtime.h>

#define CH   16
#define HID  128
#define DIM  64
#define NVOX (4 * DIM * DIM * DIM)

typedef __attribute__((ext_vector_type(8))) short short8;
typedef __attribute__((ext_vector_type(4))) float f32x4;

__device__ __forceinline__ unsigned short f2bf(float f) {
    union { float f; unsigned int u; } c; c.f = f;
    unsigned int u = c.u;
    u += 0x7FFFu + ((u >> 16) & 1u);          // round-nearest-even
    return (unsigned short)(u >> 16);
}

// Swapped-operand MFMA (kappa maps verified since R3, absmax 0.03125).
// Separable perception: per (z,y) row s = va+2vb+vc, d = va-vc over x, then
//   op1 (A_z S_y S_x) = A_i(ps), op2 (S_z A_y S_x) = S_i(pda),
//   op3 (S_z S_y A_x) = S_i(pds); 1/32 folded into staged W1 rows.
// NO min-waves clamp: (256,4) and (256,2) both forced VGPR=64 + scratch spill
// (R4: WRITE 709MB, R6: FETCH 635MB). Pressure is managed structurally:
// unroll-1 tile loop + separable accumulators. z-plane branches are
// wave-uniform and coarse (9 loads stay batched in one basic block).
__global__ __launch_bounds__(256) void nca_pass1(
    const float* __restrict__ x,  const float* __restrict__ w1,
    const float* __restrict__ b1, const float* __restrict__ w2,
    const float* __restrict__ b2, const float* __restrict__ ru,
    float* __restrict__ out, float* __restrict__ alpha_new,
    float* __restrict__ pre_life)
{
    __shared__ __align__(16) unsigned short sA1[8192];  // [n][h][g][m][j] 16KB
    __shared__ __align__(16) unsigned short sA2[2048];  // [s][g][m][j]     4KB
    __shared__ __align__(16) float sb1[HID];
    __shared__ __align__(16) float sb2[CH];

    for (int t = threadIdx.x; t < 8192; t += 256) {
        const int j = t & 7, mm = (t >> 3) & 15, gg = (t >> 7) & 3,
                  hh = (t >> 9) & 1, nn = t >> 10;
        const int op  = 2 * hh + (j & 1);
        const int row = 16 * gg + 4 * (j >> 1) + op;                // kappa1
        float wv = w1[row * HID + 16 * nn + mm];
        if (op) wv *= (1.0f / 32.0f);       // fold sobel 1/32 into W1
        sA1[t] = f2bf(wv);
    }
    for (int t = threadIdx.x; t < 2048; t += 256) {
        const int j = t & 7, mm = (t >> 3) & 15, gg = (t >> 7) & 3, ss = t >> 9;
        const int kk = 32 * ss + 16 * (j >> 2) + 4 * gg + (j & 3);  // kappa2
        sA2[t] = f2bf(w2[kk * CH + mm]);
    }
    if (threadIdx.x < HID) sb1[threadIdx.x] = b1[threadIdx.x];
    if (threadIdx.x < CH)  sb2[threadIdx.x] = b2[threadIdx.x];
    __syncthreads();

    const int lane = threadIdx.x & 63;
    const int wid  = __builtin_amdgcn_readfirstlane(threadIdx.x >> 6);
    const int m = lane & 15;
    const int g = lane >> 4;

    // each wave owns one full x-row of 64 voxels (4 MFMA tiles of 16)
    const int row = blockIdx.x * 4 + wid;     // wave-uniform (SGPR)
    const int hy = row & 63;
    const int dz = (row >> 6) & 63;
    const int bb = row >> 12;
    const int rowvox = row * 64;

    const short8* pA1 = ((const short8*)sA1) + (g * 16 + m);
    const short8* pA2 = ((const short8*)sA2) + (g * 16 + m);
    const float*  pb1 = sb1 + 4 * g;
    const float*  pb2 = sb2 + 4 * g;

    // y clamps/masks are tile-invariant (wave-uniform)
    const int yy0 = (hy > 0  ? hy - 1 : 0);
    const int yy2 = (hy < 63 ? hy + 1 : 63);
    const float oky0 = (hy > 0)  ? 1.0f : 0.0f;
    const float oky2 = (hy < 63) ? 1.0f : 0.0f;

    #pragma unroll 1
    for (int t = 0; t < 4; t++) {
        const int wx = 16 * t + m;
        const float ok0 = (wx > 0)  ? 1.0f : 0.0f;
        const float ok2 = (wx < 63) ? 1.0f : 0.0f;
        const int o1 = wx * CH + 4 * g;
        const int o0 = (wx > 0  ? wx - 1 : 0 ) * CH + 4 * g;
        const int o2 = (wx < 63 ? wx + 1 : 63) * CH + 4 * g;

        f32x4 zA = {0,0,0,0}, zB = {0,0,0,0}, zC = {0,0,0,0};
        f32x4 center = {0,0,0,0};
        float pre_max = -1e30f;

        #pragma unroll
        for (int i = 0; i < 3; i++) {
            const int zz = dz + i - 1;
            if ((unsigned)zz < 64u) {                    // uniform branch
                const float* pp =
                    x + (size_t)(((bb * 64 + zz) * 64) * 64) * CH;
                f32x4 ps = {0,0,0,0}, pds = {0,0,0,0}, pda = {0,0,0,0};
                #pragma unroll
                for (int j = 0; j < 3; j++) {
                    const int   yy  = (j == 0) ? yy0 : (j == 1) ? hy : yy2;
                    const float oky = (j == 0) ? oky0 : (j == 1) ? 1.0f : oky2;
                    const float* prow = pp + (size_t)(yy * 64) * CH;
                    f32x4 va = *(const f32x4*)(prow + o0);
                    f32x4 vb = *(const f32x4*)(prow + o1);
                    f32x4 vc = *(const f32x4*)(prow + o2);
                    va *= (ok0 * oky);
                    vb *= oky;
                    vc *= (ok2 * oky);
                    f32x4 s = va + vc;
                    #pragma unroll
                    for (int c = 0; c < 4; c++) s[c] = fmaf(2.0f, vb[c], s[c]);
                    const f32x4 d = va - vc;
                    if (j == 0)      { ps += s; pds += d; pda += s; }
                    else if (j == 1) {
                        #pragma unroll
                        for (int c = 0; c < 4; c++) {
                            ps[c]  = fmaf(2.0f, s[c], ps[c]);
                            pds[c] = fmaf(2.0f, d[c], pds[c]);
                        }
                    }
                    else             { ps += s; pds += d; pda -= s; }
                    if (i == 1 && j == 1) center = vb;
                    pre_max = fmaxf(pre_max,
                              fmaxf(fmaxf(va[3], vb[3]), vc[3]));
                }
                if (i == 0)      { zA += ps; zB += pda; zC += pds; }
                else if (i == 1) {
                    #pragma unroll
                    for (int c = 0; c < 4; c++) {
                        zB[c] = fmaf(2.0f, pda[c], zB[c]);
                        zC[c] = fmaf(2.0f, pds[c], zC[c]);
                    }
                }
                else             { zA -= ps; zB += pda; zC += pds; }
            }
        }

        short8 a0, a1;                       // B-frags: Y[m][kappa1(h,g,j)]
        #pragma unroll
        for (int c = 0; c < 4; c++) {
            a0[2 * c + 0] = (short)f2bf(center[c]);   // op0 (ident)
            a0[2 * c + 1] = (short)f2bf(zA[c]);       // op1
            a1[2 * c + 0] = (short)f2bf(zB[c]);       // op2
            a1[2 * c + 1] = (short)f2bf(zC[c]);       // op3
        }

        // stage 1: 8 n-tiles; pack relu(H) to bf16 immediately
        short8 pbf[4];
        #pragma unroll
        for (int n = 0; n < 8; n++) {
            f32x4 h = *(const f32x4*)(pb1 + 16 * n);   // broadcast LDS read
            h = __builtin_amdgcn_mfma_f32_16x16x32_bf16(pA1[(2 * n + 0) * 64], a0, h, 0, 0, 0);
            h = __builtin_amdgcn_mfma_f32_16x16x32_bf16(pA1[(2 * n + 1) * 64], a1, h, 0, 0, 0);
            #pragma unroll
            for (int r = 0; r < 4; r++)
                pbf[n >> 1][((n & 1) << 2) + r] = (short)f2bf(fmaxf(h[r], 0.0f));
        }

        // stage 2: B-frag is the lane's own packed stage-1 outputs
        f32x4 e = *(const f32x4*)pb2;
        #pragma unroll
        for (int s = 0; s < 4; s++)
            e = __builtin_amdgcn_mfma_f32_16x16x32_bf16(pA2[s * 64], pbf[s], e, 0, 0, 0);

        // epilogue: lane (m,g) owns voxel m, channels 4g..4g+3
        const int vox = rowvox + wx;
        const float mask = (ru[vox] <= 0.5f) ? 1.0f : 0.0f;
        f32x4 xn;
        #pragma unroll
        for (int r = 0; r < 4; r++) xn[r] = fmaf(e[r], mask, center[r]);
        *(f32x4*)(out + (size_t)vox * CH + 4 * g) = xn;
        if (g == 0) {
            alpha_new[vox] = xn[3];
            pre_life[vox]  = (pre_max > 0.1f) ? 1.0f : 0.0f;
        }
    }
}

__global__ __launch_bounds__(256) void nca_pass2(
    const float* __restrict__ alpha_new, const float* __restrict__ pre_life,
    float* __restrict__ out)
{
    const int idx = blockIdx.x * 256 + threadIdx.x;
    const int wx = idx & 63;
    const int hy = (idx >> 6) & 63;
    const int dz = (idx >> 12) & 63;

    float m = -1e30f;
    #pragma unroll
    for (int i = 0; i < 3; i++) {
        const int zz = dz + i - 1;
        if ((unsigned)zz >= 64u) continue;
        #pragma unroll
        for (int j = 0; j < 3; j++) {
            const int yy = hy + j - 1;
            if ((unsigned)yy >= 64u) continue;
            #pragma unroll
            for (int k = 0; k < 3; k++) {
                const int xx = wx + k - 1;
                if ((unsigned)xx >= 64u) continue;
                m = fmaxf(m, alpha_new[idx + (i - 1) * 4096 + (j - 1) * 64 + (k - 1)]);
            }
        }
    }
    const float life = (m > 0.1f && pre_life[idx] > 0.5f) ? 1.0f : 0.0f;

    float4* p = (float4*)(out + (size_t)idx * CH);
    #pragma unroll
    for (int q = 0; q < 4; q++) {
        float4 v = p[q];
        v.x *= life; v.y *= life; v.z *= life; v.w *= life;
        p[q] = v;
    }
}

extern "C" void kernel_launch(void* const* d_in, const int* in_sizes, int n_in,
                              void* d_out, int out_size, void* d_ws, size_t ws_size,
                              hipStream_t stream) {
    const float* x  = (const float*)d_in[0];
    const float* w1 = (const float*)d_in[1];
    const float* b1 = (const float*)d_in[2];
    const float* w2 = (const float*)d_in[3];
    const float* b2 = (const float*)d_in[4];
    const float* ru = (const float*)d_in[5];
    float* out = (float*)d_out;

    float* alpha_new = (float*)d_ws;
    float* pre_life  = alpha_new + NVOX;

    // 16384 x-rows, 4 rows (waves) per block
    hipLaunchKernelGGL(nca_pass1, dim3(4096), dim3(256), 0, stream,
                       x, w1, b1, w2, b2, ru, out, alpha_new, pre_life);
    hipLaunchKernelGGL(nca_pass2, dim3(NVOX / 256), dim3(256), 0, stream,
                       alpha_new, pre_life, out);
}